// Round 6
// baseline (111.972 us; speedup 1.0000x reference)
//
#include <hip/hip_runtime.h>
#include <math.h>

#define R_ROUTES 1152
#define N_CAPS 10
#define C_IN 8
#define D_DIM 16
#define B_BATCH 128
#define JD 160                      // N_CAPS * D_DIM
#define KK 9216                     // R_ROUTES * C_IN (GEMM K)
#define KSPLIT 48                   // 24 routes = 192 k per split
#define RS 24                       // routes per k-split
#define NG 5                        // jd groups of 32
#define BH 2                        // batch halves
#define SPART 20480                 // floats per split-K partial (128*160)

typedef __attribute__((ext_vector_type(8))) short short8;   // 8 bf16 (4 VGPRs)
typedef __attribute__((ext_vector_type(4))) float f32x4;    // MFMA accumulator

__device__ inline unsigned short f2bf(float f) {            // RNE fp32 -> bf16
    unsigned int u = __float_as_uint(f);
    unsigned int r = u + 0x7FFFu + ((u >> 16) & 1u);
    return (unsigned short)(r >> 16);
}
__device__ inline float bf2f(unsigned short h) {
    return __uint_as_float(((unsigned int)h) << 16);
}

// ---------------------------------------------------------------------------
// ws layout (byte offsets):
//   s0   fp32 [128][160]       @ 0        (81920)
//   s1   fp32 [128][160]       @ 81920    (81920)   [s0+s1 zeroed in d1]
//   b_ij fp32 [1152][10]       @ 163840   (46080; stored by va1, += by va2)
//   ctab fp32 [1152][10]       @ 209920   (46080; softmax(b) written by k_va)
//   xT   bf16 [9216][128]      @ 256000   (2359296; M2 A-operand)
//   s2p  fp32 [48][128][160]   @ 2615296  (3932160; iter3 plain-store split-K)
// Lesson log:
//  R7/R9 (112.4us, 7 dispatches): atomic split-K KSPLIT=48. R10/R11: atomic
//    throughput exonerated. R12: 2x waves NEUTRAL -> not occupancy-starved.
//  R13 REGRESSED (150us): per-block redundant full agreement = 55us/dispatch.
//  R14 REGRESSED (177us): serial single-block agent-scalar tail = 15-25us x3.
//  R15 REGRESSED (148us): 10-sibling agent ACQ-spin barrier; fused 42us vs
//    ~30 unfused. FIRM: in-kernel cross-block sync >> 7us dispatch gap.
//  R16 (111.6us == R0's 112): 7 dispatches both; kernel internals barely
//    move the total -> per-dispatch fixed cost ~8us x 6 gaps + ~60us kernels.
//  R17 (112 prediction miss -> container infra failure; resubmitted):
//    - transpose moved from iter1's dispatch (was elongating it) into the
//      ~idle zero dispatch.  d2 becomes pure iter1.
//    - iter3: plain-store split-K partials (no atomics, no s2 zero); k_final
//      reduces 48 partials (3.9MB, no redundancy - the one consumer where
//      partials are affordable, unlike 288-block va which reads s 288x).
//    - k_va phase B: unrolled 5-tile loop -> 5 independent MFMA chains
//      pipeline; same-mt A-fragments CSE.
// ---------------------------------------------------------------------------

// d1: blocks 0..287 transpose x -> xT; blocks 288..327 zero s0+s1
__global__ __launch_bounds__(256) void k_prep0(
    const float* __restrict__ x, unsigned short* __restrict__ xT,
    f32x4* __restrict__ zbase) {
    __shared__ float tile[32][33];
    int id = blockIdx.x, t = threadIdx.x;
    if (id < 288) {                           // ---- transpose role ----
        int bx = id;                          // rc tile 0..287
        int tx = t & 31, ty = t >> 5;
        for (int by = 0; by < 4; by++) {
            if (by) __syncthreads();
#pragma unroll
            for (int i = 0; i < 4; i++) {
                int row = ty + i * 8;         // b_local
                tile[row][tx] = x[(size_t)(by * 32 + row) * KK + bx * 32 + tx];
            }
            __syncthreads();
#pragma unroll
            for (int i = 0; i < 4; i++) {
                int row = ty + i * 8;         // rc_local
                xT[(size_t)(bx * 32 + row) * B_BATCH + by * 32 + tx] = f2bf(tile[tx][row]);
            }
        }
        return;
    }
    // ---- zero role: s0+s1 = 163840 B = 10240 f32x4 over 40 blocks ----
    int idx = (id - 288) * 256 + t;
    zbase[idx] = (f32x4){0.f, 0.f, 0.f, 0.f};
}

// One routing iteration's weighted-sum GEMM. No LDS, no barriers.
// B-fragments built from global W in regs (fragment route rl = st*4+quad),
// A from x fp32 hi/lo split (R15/R16-verified).
// FIRST: c = 0.1.  STORE: plain-store split-K partials (iter3) vs atomicAdd.
template <int FIRST, int STORE>
__global__ __launch_bounds__(256) void k_iter(
    const float* __restrict__ x, const float* __restrict__ W,
    const float* __restrict__ ctab, float* __restrict__ s) {
    int t = threadIdx.x;
    int ks = blockIdx.x, ng = blockIdx.y, bh = blockIdx.z;
    int r0 = ks * RS, jd0 = ng * 32, b_base = bh * 64;
    int w = t >> 6, l = t & 63, row = l & 15, quad = l >> 4;
    const float* px = x + (size_t)(b_base + w * 16 + row) * KK + ks * 192;
    f32x4 acc0 = {0,0,0,0}, acc1 = {0,0,0,0};
#pragma unroll
    for (int st = 0; st < 6; st++) {          // K = 192 = 6 steps of 32
        int rr = r0 + st * 4 + quad;          // route of this fragment
        float c0 = FIRST ? 0.1f : ctab[rr * N_CAPS + (jd0 >> 4)];
        float c1 = FIRST ? 0.1f : ctab[rr * N_CAPS + (jd0 >> 4) + 1];
        const float4* wp0 = (const float4*)(W + ((size_t)rr * JD + jd0 + row) * C_IN);
        const float4* wp1 = (const float4*)(W + ((size_t)rr * JD + jd0 + 16 + row) * C_IN);
        float4 wa = wp0[0], wb = wp0[1], wc = wp1[0], wd = wp1[1];
        float wv0[8] = {wa.x,wa.y,wa.z,wa.w, wb.x,wb.y,wb.z,wb.w};
        float wv1[8] = {wc.x,wc.y,wc.z,wc.w, wd.x,wd.y,wd.z,wd.w};
        short8 Bh0, Bh1;
#pragma unroll
        for (int i = 0; i < 8; i++) {
            Bh0[i] = (short)f2bf(wv0[i] * c0);
            Bh1[i] = (short)f2bf(wv1[i] * c1);
        }
        float4 x0 = *(const float4*)(px + st * 32 + quad * 8);
        float4 x1 = *(const float4*)(px + st * 32 + quad * 8 + 4);
        float xv[8] = {x0.x,x0.y,x0.z,x0.w, x1.x,x1.y,x1.z,x1.w};
        short8 Ah, Al;
#pragma unroll
        for (int i = 0; i < 8; i++) {
            unsigned short h = f2bf(xv[i]);
            Ah[i] = (short)h;
            Al[i] = (short)f2bf(xv[i] - bf2f(h));
        }
        acc0 = __builtin_amdgcn_mfma_f32_16x16x32_bf16(Ah, Bh0, acc0, 0, 0, 0);
        acc0 = __builtin_amdgcn_mfma_f32_16x16x32_bf16(Al, Bh0, acc0, 0, 0, 0);
        acc1 = __builtin_amdgcn_mfma_f32_16x16x32_bf16(Ah, Bh1, acc1, 0, 0, 0);
        acc1 = __builtin_amdgcn_mfma_f32_16x16x32_bf16(Al, Bh1, acc1, 0, 0, 0);
    }
    if (STORE) {                              // plain-store split-K (iter3)
        float* sp = s + (size_t)ks * SPART;
#pragma unroll
        for (int i = 0; i < 4; i++) {
            int b0 = b_base + w * 16 + quad * 4 + i;
            sp[(size_t)b0 * JD + jd0 + row]      = acc0[i];
            sp[(size_t)b0 * JD + jd0 + 16 + row] = acc1[i];
        }
    } else {
#pragma unroll
        for (int i = 0; i < 4; i++) {         // C/D: col=lane&15 (jd), row=quad*4+i (b)
            int b0 = b_base + w * 16 + quad * 4 + i;
            atomicAdd(&s[(size_t)b0 * JD + jd0 + row],      acc0[i]);
            atomicAdd(&s[(size_t)b0 * JD + jd0 + 16 + row], acc1[i]);
        }
    }
}

// Agreement + softmax: squash(s_prev)->vb, M2 via MFMA with in-register W
// contract (R13/R15-verified), b_new for this block's 4 routes, softmax->ctab.
// ACCUM=0 (va1): b_ij = upd (store).  ACCUM=1 (va2): b_ij + upd.
template <int ACCUM>
__global__ __launch_bounds__(256) void k_va(
    const unsigned short* __restrict__ xT, const float* __restrict__ s_prev,
    const float* __restrict__ W, float* __restrict__ b_ij,
    float* __restrict__ ctab) {
    __shared__ unsigned short vb[JD][136];    // [jd][b], +8 pad (43520 B)
    __shared__ float bnew[4][N_CAPS];
    int t = threadIdx.x;
    int r0 = blockIdx.x * 4, rc0 = blockIdx.x * 32;

    // --- squash(s_prev) -> vb (R15/R16-verified float4 version) ----------
#pragma unroll
    for (int q = 0; q < 5; q++) {
        int pi = t * 5 + q;                   // (b, j) pair, 1280 total
        int b = pi / N_CAPS, j = pi % N_CAPS;
        const float4* sp4 = (const float4*)(s_prev + (size_t)b * JD + j * D_DIM);
        float4 a0 = sp4[0], a1 = sp4[1], a2 = sp4[2], a3 = sp4[3];
        float sv[D_DIM] = {a0.x,a0.y,a0.z,a0.w, a1.x,a1.y,a1.z,a1.w,
                           a2.x,a2.y,a2.z,a2.w, a3.x,a3.y,a3.z,a3.w};
        float sqn = 0.f;
#pragma unroll
        for (int d = 0; d < D_DIM; d++) sqn = fmaf(sv[d], sv[d], sqn);
        float scale = sqn / ((1.f + sqn) * sqrtf(sqn));
#pragma unroll
        for (int d = 0; d < D_DIM; d++)
            vb[j * D_DIM + d][b] = f2bf(sv[d] * scale);
    }
    __syncthreads();

    int w = t >> 6, l = t & 63, row = l & 15, quad = l >> 4;
    int rhalf = l >> 5, cbase = (quad & 1) * 4;

    // --- M2 tiles + in-register W contract, 5 tiles/wave UNROLLED --------
    // tile (mt,nt): acc[i] = M2[rc=mt*16+quad*4+i][jd=nt*16+row];
    // route = r0+2mt+rhalf, c = cbase+i; reduce over 32-lane half.
#pragma unroll
    for (int jt = 0; jt < 5; jt++) {          // u = jt*4 + w: 5 independent chains
        int u = jt * 4 + w;
        int mt = u / 10, nt = u % 10;
        const short8* pa = (const short8*)(xT + (size_t)(rc0 + mt * 16 + row) * B_BATCH);
        f32x4 acc = {0,0,0,0};
#pragma unroll
        for (int st = 0; st < 4; st++)        // K = 128 = 4 steps of 32
            acc = __builtin_amdgcn_mfma_f32_16x16x32_bf16(
                pa[st * 4 + quad],
                *(const short8*)&vb[nt * 16 + row][st * 32 + quad * 8],
                acc, 0, 0, 0);
        int r = r0 + 2 * mt + rhalf;
        const float* wp = W + ((size_t)r * JD + nt * 16 + row) * C_IN + cbase;
        float4 w4 = *(const float4*)wp;
        float part = acc[0]*w4.x + acc[1]*w4.y + acc[2]*w4.z + acc[3]*w4.w;
#pragma unroll
        for (int off = 1; off < 32; off <<= 1) part += __shfl_xor(part, off, 32);
        if ((l & 31) == 0) bnew[2 * mt + rhalf][nt] = part * (1.f / (float)B_BATCH);
    }
    __syncthreads();

    // --- softmax for this block's 4 routes -> ctab (and b_ij chain) ------
    if (t < 4) {
        float bj[N_CAPS], m = -1e30f;
#pragma unroll
        for (int j = 0; j < N_CAPS; j++) {
            float base = ACCUM ? b_ij[(r0 + t) * N_CAPS + j] : 0.f;
            bj[j] = base + bnew[t][j];
            m = fmaxf(m, bj[j]);
        }
        if (!ACCUM) {
#pragma unroll
            for (int j = 0; j < N_CAPS; j++) b_ij[(r0 + t) * N_CAPS + j] = bj[j];
        }
        float sum = 0.f;
#pragma unroll
        for (int j = 0; j < N_CAPS; j++) { bj[j] = expf(bj[j] - m); sum += bj[j]; }
        float inv = 1.f / sum;
#pragma unroll
        for (int j = 0; j < N_CAPS; j++) ctab[(r0 + t) * N_CAPS + j] = bj[j] * inv;
    }
}

// final: reduce 48 split-K partials + squash -> out
__global__ __launch_bounds__(320) void k_final(
    const float* __restrict__ s2p, float* __restrict__ out) {
    int t = threadIdx.x;                      // 320 = 2 b x 160 jd
    int bloc = t / JD, jd = t % JD;
    int b = blockIdx.x * 2 + bloc;
    float acc = 0.f;
#pragma unroll
    for (int ks = 0; ks < KSPLIT; ks++)
        acc += s2p[(size_t)ks * SPART + (size_t)b * JD + jd];
    float sq = acc * acc;                     // lane%16 == jd%16 -> width-16 xor
#pragma unroll
    for (int off = 1; off < 16; off <<= 1) sq += __shfl_xor(sq, off, 16);
    float scale = sq / ((1.f + sq) * sqrtf(sq));
    out[(size_t)b * JD + jd] = acc * scale;
}

extern "C" void kernel_launch(void* const* d_in, const int* in_sizes, int n_in,
                              void* d_out, int out_size, void* d_ws, size_t ws_size,
                              hipStream_t stream) {
    const float* x = (const float*)d_in[0];   // [128,1152,8]
    const float* W = (const float*)d_in[1];   // [1,1152,10,16,8]
    float* out = (float*)d_out;               // [128,10,16,1]
    char* ws = (char*)d_ws;

    float*          s0   = (float*)(ws + 0);
    float*          s1   = (float*)(ws + 81920);
    float*          b_ij = (float*)(ws + 163840);
    float*          ctab = (float*)(ws + 209920);
    unsigned short* xT   = (unsigned short*)(ws + 256000);
    float*          s2p  = (float*)(ws + 2615296);

    // d1: transpose x->xT + zero s0,s1
    k_prep0<<<328, 256, 0, stream>>>(x, xT, (f32x4*)ws);

    // d2: iter1 (c=0.1) -> s0 (atomic)
    k_iter<1, 0><<<dim3(KSPLIT, NG, BH), 256, 0, stream>>>(x, W, nullptr, s0);

    // d3: va1 -> b_ij (store), ctab
    k_va<0><<<288, 256, 0, stream>>>(xT, s0, W, b_ij, ctab);

    // d4: iter2 -> s1 (atomic)
    k_iter<0, 0><<<dim3(KSPLIT, NG, BH), 256, 0, stream>>>(x, W, ctab, s1);

    // d5: va2 -> ctab (b_ij + upd2)
    k_va<1><<<288, 256, 0, stream>>>(xT, s1, W, b_ij, ctab);

    // d6: iter3 -> s2p (plain-store split-K)
    k_iter<0, 1><<<dim3(KSPLIT, NG, BH), 256, 0, stream>>>(x, W, ctab, s2p);

    // d7: reduce partials + final squash
    k_final<<<64, 320, 0, stream>>>(s2p, out);
}